// Round 1
// baseline (339.728 us; speedup 1.0000x reference)
//
#include <hip/hip_runtime.h>

#define BSZ  8192
#define DDIM 256
#define NCLS 1024
#define BM 128
#define BN 128
#define BK 64

typedef float f32x4 __attribute__((ext_vector_type(4)));
typedef short bf16x8 __attribute__((ext_vector_type(8)));

__device__ __forceinline__ unsigned short f32_to_bf16(float f) {
    unsigned int u = __float_as_uint(f);
    u += 0x7fffu + ((u >> 16) & 1u);   // RNE
    return (unsigned short)(u >> 16);
}

// ---------------- zero ws accumulators ----------------
__global__ __launch_bounds__(256) void zero_kernel(float* __restrict__ acc,
                                                   int* __restrict__ hist) {
    const int i = blockIdx.x * 256 + threadIdx.x;
    if (i < BSZ * 4) acc[i] = 0.0f;
    if (i < NCLS) hist[i] = 0;
}

// ---------------- label histogram ----------------
__global__ __launch_bounds__(256) void hist_kernel(const int* __restrict__ labels,
                                                   int* __restrict__ hist) {
    const int i = blockIdx.x * 256 + threadIdx.x;
    if (i < BSZ) atomicAdd(&hist[labels[i]], 1);
}

// ---------------- L2-normalize rows, emit bf16 ----------------
__global__ __launch_bounds__(256) void norm_kernel(const float* __restrict__ feat,
                                                   unsigned short* __restrict__ anchor) {
    const int wid  = threadIdx.x >> 6;
    const int lane = threadIdx.x & 63;
    const int row  = blockIdx.x * 4 + wid;
    const float4 v = ((const float4*)(feat + (size_t)row * DDIM))[lane];
    float ss = v.x * v.x + v.y * v.y + v.z * v.z + v.w * v.w;
    #pragma unroll
    for (int off = 32; off > 0; off >>= 1) ss += __shfl_xor(ss, off, 64);
    const float inv = rsqrtf(ss);
    ushort4 o;
    o.x = f32_to_bf16(v.x * inv);
    o.y = f32_to_bf16(v.y * inv);
    o.z = f32_to_bf16(v.z * inv);
    o.w = f32_to_bf16(v.w * inv);
    ((ushort4*)(anchor + (size_t)row * DDIM))[lane] = o;
}

// ---------------- async global -> LDS, 16B/lane ----------------
__device__ __forceinline__ void gload_lds16(const unsigned short* g, unsigned short* l) {
    __builtin_amdgcn_global_load_lds(
        (const __attribute__((address_space(1))) void*)g,
        (__attribute__((address_space(3))) void*)l, 16, 0, 0);
}

// ---------------- fused sim-tile + loss partials ----------------
// acc[row*4 + {0:denom, 1:S1, 2:W1, 3:S2}]
__global__ __launch_bounds__(256) void simloss_kernel(
    const unsigned short* __restrict__ anchor,
    const int* __restrict__ labels,
    float* __restrict__ acc)
{
    __shared__ __align__(16) unsigned short As[BM * BK];
    __shared__ __align__(16) unsigned short Bs[BN * BK];
    __shared__ int rowLab[BM];
    __shared__ int colLab[BN];

    const int It = blockIdx.x;
    const int Jt = blockIdx.y;
    const int I0 = It * BM;
    const int J0 = Jt * BN;

    const int tid  = threadIdx.x;
    const int wid  = tid >> 6;
    const int lane = tid & 63;
    const int waveM = (wid >> 1) * 64;   // 2x2 wave grid over 128x128
    const int waveN = (wid & 1) * 64;
    const int cl = lane & 15;            // column within 16x16 frag
    const int rg = lane >> 4;            // row group (rows rg*4 + reg)

    if (tid < BM) rowLab[tid] = labels[I0 + tid];
    else          colLab[tid - BM] = labels[J0 + tid - BM];

    f32x4 c_acc[4][4];
    #pragma unroll
    for (int a = 0; a < 4; a++)
        #pragma unroll
        for (int b = 0; b < 4; b++)
            c_acc[a][b] = (f32x4){0.f, 0.f, 0.f, 0.f};

    const int ldrow = lane >> 3;        // 0..7 within 8-row chunk
    const int ldcol = (lane & 7) * 8;   // element offset (8 bf16 = 16B)

    for (int kc = 0; kc < DDIM; kc += BK) {
        // stage A(128x64) and B(128x64): 16 x 1KB wave-chunks each
        #pragma unroll
        for (int q = 0; q < 4; q++) {
            const int ci = wid * 4 + q;            // chunk 0..15 -> rows ci*8..ci*8+7
            const int r  = ci * 8 + ldrow;
            gload_lds16(anchor + (size_t)(I0 + r) * DDIM + kc + ldcol, &As[ci * 512]);
            gload_lds16(anchor + (size_t)(J0 + r) * DDIM + kc + ldcol, &Bs[ci * 512]);
        }
        __syncthreads();
        #pragma unroll
        for (int ks = 0; ks < 2; ks++) {
            bf16x8 af[4], bfr[4];
            #pragma unroll
            for (int f = 0; f < 4; f++) {
                af[f]  = *(const bf16x8*)&As[(waveM + f * 16 + cl) * BK + ks * 32 + rg * 8];
                bfr[f] = *(const bf16x8*)&Bs[(waveN + f * 16 + cl) * BK + ks * 32 + rg * 8];
            }
            #pragma unroll
            for (int fr = 0; fr < 4; fr++)
                #pragma unroll
                for (int fc = 0; fc < 4; fc++)
                    c_acc[fr][fc] = __builtin_amdgcn_mfma_f32_16x16x32_bf16(
                        af[fr], bfr[fc], c_acc[fr][fc], 0, 0, 0);
        }
        __syncthreads();
    }

    // epilogue: per-entry weights/exp, per-row partial sums
    const float INV_T = 14.2857142857142857f;   // 1/0.07
    const float LOG2E = 1.4426950408889634f;

    #pragma unroll
    for (int fr = 0; fr < 4; fr++) {
        float dsum[4], s1[4], w1[4], s2[4];
        #pragma unroll
        for (int r = 0; r < 4; r++) { dsum[r] = 0.f; s1[r] = 0.f; w1[r] = 0.f; s2[r] = 0.f; }
        #pragma unroll
        for (int fc = 0; fc < 4; fc++) {
            const int gj = J0 + waveN + fc * 16 + cl;
            const int lj = colLab[waveN + fc * 16 + cl];
            const f32x4 c = c_acc[fr][fc];
            #pragma unroll
            for (int r = 0; r < 4; r++) {
                const int ridx = waveM + fr * 16 + rg * 4 + r;
                const int gi = I0 + ridx;
                const int li = rowLab[ridx];
                const float s  = c[r];
                const float lp = (s - 1.0f) * INV_T;          // logits - m, m = 1/T
                const float e  = exp2f(lp * LOG2E);           // exp(logits - m)
                const float wp = fmaxf(1.5f - s, 1.0f);       // pos weight (continuous)
                const float wn = fmaxf(fmaf(s, 1.42857142857142857f, 0.571428571428571f), 1.0f);
                const bool offd = (gi != gj);
                const bool pos  = (li == lj);
                const float moff = offd ? 1.0f : 0.0f;
                const float mp   = (offd && pos) ? 1.0f : 0.0f;
                const float mn   = moff - mp;
                dsum[r] += moff * e;
                s1[r] = fmaf(mp * wp, lp, s1[r]);
                w1[r] += mp * wp;
                s2[r] = fmaf(mn * wn, e, s2[r]);
            }
        }
        // reduce across the 16 lanes that share rows (sum over columns)
        #pragma unroll
        for (int r = 0; r < 4; r++) {
            #pragma unroll
            for (int off = 1; off < 16; off <<= 1) {
                dsum[r] += __shfl_xor(dsum[r], off, 64);
                s1[r]   += __shfl_xor(s1[r],   off, 64);
                w1[r]   += __shfl_xor(w1[r],   off, 64);
                s2[r]   += __shfl_xor(s2[r],   off, 64);
            }
        }
        if (cl == 0) {
            #pragma unroll
            for (int r = 0; r < 4; r++) {
                const int gi = I0 + waveM + fr * 16 + rg * 4 + r;
                float* a = acc + (size_t)gi * 4;
                atomicAdd(a + 0, dsum[r]);
                atomicAdd(a + 1, s1[r]);
                atomicAdd(a + 2, w1[r]);
                atomicAdd(a + 3, s2[r]);
            }
        }
    }
}

// ---------------- final reduction ----------------
__global__ __launch_bounds__(256) void finalize_kernel(
    const float* __restrict__ acc, const int* __restrict__ labels,
    const int* __restrict__ hist, float* __restrict__ out)
{
    double pos_acc = 0.0, neg_acc = 0.0;
    for (int i = threadIdx.x; i < BSZ; i += 256) {
        const float denom = acc[i * 4 + 0];
        const float S1    = acc[i * 4 + 1];
        const float W1    = acc[i * 4 + 2];
        const float S2    = acc[i * 4 + 3];
        const int h = hist[labels[i]];
        const float pc = fmaxf((float)(h - 1), 1.0f);
        const float nc = fmaxf((float)(BSZ - h), 1.0f);
        const float ld = logf(denom);
        pos_acc += (double)((S1 - ld * W1) / pc);
        neg_acc += (double)((S2 / denom) / nc);
    }
    __shared__ double sp[256], sn[256];
    sp[threadIdx.x] = pos_acc;
    sn[threadIdx.x] = neg_acc;
    __syncthreads();
    for (int s = 128; s > 0; s >>= 1) {
        if (threadIdx.x < s) {
            sp[threadIdx.x] += sp[threadIdx.x + s];
            sn[threadIdx.x] += sn[threadIdx.x + s];
        }
        __syncthreads();
    }
    if (threadIdx.x == 0) {
        const double loss = -sp[0] / (double)BSZ + 0.3 * (sn[0] / (double)BSZ);
        out[0] = (float)loss;
    }
}

extern "C" void kernel_launch(void* const* d_in, const int* in_sizes, int n_in,
                              void* d_out, int out_size, void* d_ws, size_t ws_size,
                              hipStream_t stream) {
    const float* feat  = (const float*)d_in[0];
    const int* labels  = (const int*)d_in[1];
    float* out = (float*)d_out;

    char* ws = (char*)d_ws;
    unsigned short* anchor = (unsigned short*)ws;                       // 4 MB bf16
    const size_t anchorBytes = (size_t)BSZ * DDIM * sizeof(unsigned short);
    float* acc = (float*)(ws + anchorBytes);                            // 128 KB
    const size_t accBytes = (size_t)BSZ * 4 * sizeof(float);
    int* hist = (int*)(ws + anchorBytes + accBytes);                    // 4 KB

    zero_kernel<<<(BSZ * 4 + 255) / 256, 256, 0, stream>>>(acc, hist);
    hist_kernel<<<BSZ / 256, 256, 0, stream>>>(labels, hist);
    norm_kernel<<<BSZ / 4, 256, 0, stream>>>(feat, anchor);
    dim3 grid(BSZ / BM, BSZ / BN);
    simloss_kernel<<<grid, 256, 0, stream>>>(anchor, labels, acc);
    finalize_kernel<<<1, 256, 0, stream>>>(acc, labels, hist, out);
}

// Round 2
// 184.485 us; speedup vs baseline: 1.8415x; 1.8415x over previous
//
#include <hip/hip_runtime.h>

#define BSZ  8192
#define DDIM 256
#define NCLS 1024
#define BM 128
#define BN 128
#define BK 64
#define NJT (BSZ / BN)   // 64 column tiles

typedef float f32x4 __attribute__((ext_vector_type(4)));
typedef short bf16x8 __attribute__((ext_vector_type(8)));

__device__ __forceinline__ unsigned short f32_to_bf16(float f) {
    unsigned int u = __float_as_uint(f);
    u += 0x7fffu + ((u >> 16) & 1u);   // RNE
    return (unsigned short)(u >> 16);
}

// ---------------- zero hist ----------------
__global__ __launch_bounds__(256) void zero_kernel(int* __restrict__ hist) {
    const int i = blockIdx.x * 256 + threadIdx.x;
    if (i < NCLS) hist[i] = 0;
}

// ---------------- label histogram ----------------
__global__ __launch_bounds__(256) void hist_kernel(const int* __restrict__ labels,
                                                   int* __restrict__ hist) {
    const int i = blockIdx.x * 256 + threadIdx.x;
    if (i < BSZ) atomicAdd(&hist[labels[i]], 1);
}

// ---------------- L2-normalize rows, emit bf16 ----------------
__global__ __launch_bounds__(256) void norm_kernel(const float* __restrict__ feat,
                                                   unsigned short* __restrict__ anchor) {
    const int wid  = threadIdx.x >> 6;
    const int lane = threadIdx.x & 63;
    const int row  = blockIdx.x * 4 + wid;
    const float4 v = ((const float4*)(feat + (size_t)row * DDIM))[lane];
    float ss = v.x * v.x + v.y * v.y + v.z * v.z + v.w * v.w;
    #pragma unroll
    for (int off = 32; off > 0; off >>= 1) ss += __shfl_xor(ss, off, 64);
    const float inv = rsqrtf(ss);
    ushort4 o;
    o.x = f32_to_bf16(v.x * inv);
    o.y = f32_to_bf16(v.y * inv);
    o.z = f32_to_bf16(v.z * inv);
    o.w = f32_to_bf16(v.w * inv);
    ((ushort4*)(anchor + (size_t)row * DDIM))[lane] = o;
}

// ---------------- async global -> LDS, 16B/lane ----------------
__device__ __forceinline__ void gload_lds16(const unsigned short* g, unsigned short* l) {
    __builtin_amdgcn_global_load_lds(
        (const __attribute__((address_space(1))) void*)g,
        (__attribute__((address_space(3))) void*)l, 16, 0, 0);
}

// ---------------- fused sim-tile + loss partials ----------------
// part[Jt][row][{0:denom,1:S1,2:W1,3:S2}]  (no atomics)
__global__ __launch_bounds__(256) void simloss_kernel(
    const unsigned short* __restrict__ anchor,
    const int* __restrict__ labels,
    float* __restrict__ part)
{
    __shared__ __align__(16) unsigned short As[BM * BK];
    __shared__ __align__(16) unsigned short Bs[BN * BK];
    __shared__ int rowLab[BM];
    __shared__ int colLab[BN];
    __shared__ float blockPart[2][BM][4];   // [waveN-half][row][qty], 4 KB

    const int It = blockIdx.x;
    const int Jt = blockIdx.y;
    const int I0 = It * BM;
    const int J0 = Jt * BN;

    const int tid  = threadIdx.x;
    const int wid  = tid >> 6;
    const int lane = tid & 63;
    const int waveM = (wid >> 1) * 64;   // 2x2 wave grid over 128x128
    const int waveN = (wid & 1) * 64;
    const int cl = lane & 15;            // column within 16x16 frag
    const int rg = lane >> 4;            // row group (rows rg*4 + reg)

    if (tid < BM) rowLab[tid] = labels[I0 + tid];
    else          colLab[tid - BM] = labels[J0 + tid - BM];

    f32x4 c_acc[4][4];
    #pragma unroll
    for (int a = 0; a < 4; a++)
        #pragma unroll
        for (int b = 0; b < 4; b++)
            c_acc[a][b] = (f32x4){0.f, 0.f, 0.f, 0.f};

    const int ldrow = lane >> 3;        // 0..7 within 8-row chunk
    const int ldcol = (lane & 7) * 8;   // element offset (8 bf16 = 16B)

    for (int kc = 0; kc < DDIM; kc += BK) {
        #pragma unroll
        for (int q = 0; q < 4; q++) {
            const int ci = wid * 4 + q;            // chunk 0..15 -> rows ci*8..ci*8+7
            const int r  = ci * 8 + ldrow;
            gload_lds16(anchor + (size_t)(I0 + r) * DDIM + kc + ldcol, &As[ci * 512]);
            gload_lds16(anchor + (size_t)(J0 + r) * DDIM + kc + ldcol, &Bs[ci * 512]);
        }
        __syncthreads();
        #pragma unroll
        for (int ks = 0; ks < 2; ks++) {
            bf16x8 af[4], bfr[4];
            #pragma unroll
            for (int f = 0; f < 4; f++) {
                af[f]  = *(const bf16x8*)&As[(waveM + f * 16 + cl) * BK + ks * 32 + rg * 8];
                bfr[f] = *(const bf16x8*)&Bs[(waveN + f * 16 + cl) * BK + ks * 32 + rg * 8];
            }
            #pragma unroll
            for (int fr = 0; fr < 4; fr++)
                #pragma unroll
                for (int fc = 0; fc < 4; fc++)
                    c_acc[fr][fc] = __builtin_amdgcn_mfma_f32_16x16x32_bf16(
                        af[fr], bfr[fc], c_acc[fr][fc], 0, 0, 0);
        }
        __syncthreads();
    }

    // epilogue: per-entry weights/exp, per-row partial sums
    const float INV_T = 14.2857142857142857f;   // 1/0.07
    const float LOG2E = 1.4426950408889634f;

    #pragma unroll
    for (int fr = 0; fr < 4; fr++) {
        float dsum[4], s1[4], w1[4], s2[4];
        #pragma unroll
        for (int r = 0; r < 4; r++) { dsum[r] = 0.f; s1[r] = 0.f; w1[r] = 0.f; s2[r] = 0.f; }
        #pragma unroll
        for (int fc = 0; fc < 4; fc++) {
            const int gj = J0 + waveN + fc * 16 + cl;
            const int lj = colLab[waveN + fc * 16 + cl];
            const f32x4 c = c_acc[fr][fc];
            #pragma unroll
            for (int r = 0; r < 4; r++) {
                const int ridx = waveM + fr * 16 + rg * 4 + r;
                const int gi = I0 + ridx;
                const int li = rowLab[ridx];
                const float s  = c[r];
                const float lp = (s - 1.0f) * INV_T;          // logits - m, m = 1/T
                const float e  = exp2f(lp * LOG2E);           // exp(logits - m)
                const float wp = fmaxf(1.5f - s, 1.0f);       // pos weight (continuous)
                const float wn = fmaxf(fmaf(s, 1.42857142857142857f, 0.571428571428571f), 1.0f);
                const bool offd = (gi != gj);
                const bool pos  = (li == lj);
                const float moff = offd ? 1.0f : 0.0f;
                const float mp   = (offd && pos) ? 1.0f : 0.0f;
                const float mn   = moff - mp;
                dsum[r] += moff * e;
                s1[r] = fmaf(mp * wp, lp, s1[r]);
                w1[r] += mp * wp;
                s2[r] = fmaf(mn * wn, e, s2[r]);
            }
        }
        // reduce across the 16 lanes that share rows (sum over columns)
        #pragma unroll
        for (int r = 0; r < 4; r++) {
            #pragma unroll
            for (int off = 1; off < 16; off <<= 1) {
                dsum[r] += __shfl_xor(dsum[r], off, 64);
                s1[r]   += __shfl_xor(s1[r],   off, 64);
                w1[r]   += __shfl_xor(w1[r],   off, 64);
                s2[r]   += __shfl_xor(s2[r],   off, 64);
            }
        }
        if (cl == 0) {
            #pragma unroll
            for (int r = 0; r < 4; r++) {
                const int row = waveM + fr * 16 + rg * 4 + r;
                float* p = &blockPart[wid & 1][row][0];
                p[0] = dsum[r];
                p[1] = s1[r];
                p[2] = w1[r];
                p[3] = s2[r];
            }
        }
    }
    __syncthreads();

    // combine the two column-wave halves, store 2KB coalesced (no atomics)
    if (tid < BM) {
        float4 v;
        v.x = blockPart[0][tid][0] + blockPart[1][tid][0];
        v.y = blockPart[0][tid][1] + blockPart[1][tid][1];
        v.z = blockPart[0][tid][2] + blockPart[1][tid][2];
        v.w = blockPart[0][tid][3] + blockPart[1][tid][3];
        ((float4*)part)[(size_t)Jt * BSZ + I0 + tid] = v;
    }
}

// ---------------- reduce partials over Jt ----------------
__global__ __launch_bounds__(256) void reduce_kernel(const float* __restrict__ part,
                                                     float* __restrict__ acc) {
    const int idx = blockIdx.x * 256 + threadIdx.x;   // 0 .. BSZ*4-1
    float s = 0.f;
    #pragma unroll 8
    for (int j = 0; j < NJT; j++) s += part[(size_t)j * (BSZ * 4) + idx];
    acc[idx] = s;
}

// ---------------- final reduction ----------------
__global__ __launch_bounds__(256) void finalize_kernel(
    const float* __restrict__ acc, const int* __restrict__ labels,
    const int* __restrict__ hist, float* __restrict__ out)
{
    double pos_acc = 0.0, neg_acc = 0.0;
    for (int i = threadIdx.x; i < BSZ; i += 256) {
        const float denom = acc[i * 4 + 0];
        const float S1    = acc[i * 4 + 1];
        const float W1    = acc[i * 4 + 2];
        const float S2    = acc[i * 4 + 3];
        const int h = hist[labels[i]];
        const float pc = fmaxf((float)(h - 1), 1.0f);
        const float nc = fmaxf((float)(BSZ - h), 1.0f);
        const float ld = logf(denom);
        pos_acc += (double)((S1 - ld * W1) / pc);
        neg_acc += (double)((S2 / denom) / nc);
    }
    __shared__ double sp[256], sn[256];
    sp[threadIdx.x] = pos_acc;
    sn[threadIdx.x] = neg_acc;
    __syncthreads();
    for (int s = 128; s > 0; s >>= 1) {
        if (threadIdx.x < s) {
            sp[threadIdx.x] += sp[threadIdx.x + s];
            sn[threadIdx.x] += sn[threadIdx.x + s];
        }
        __syncthreads();
    }
    if (threadIdx.x == 0) {
        const double loss = -sp[0] / (double)BSZ + 0.3 * (sn[0] / (double)BSZ);
        out[0] = (float)loss;
    }
}

extern "C" void kernel_launch(void* const* d_in, const int* in_sizes, int n_in,
                              void* d_out, int out_size, void* d_ws, size_t ws_size,
                              hipStream_t stream) {
    const float* feat  = (const float*)d_in[0];
    const int* labels  = (const int*)d_in[1];
    float* out = (float*)d_out;

    char* ws = (char*)d_ws;
    unsigned short* anchor = (unsigned short*)ws;                       // 4 MB bf16
    const size_t anchorBytes = (size_t)BSZ * DDIM * sizeof(unsigned short);
    float* part = (float*)(ws + anchorBytes);                           // 64*8192*4 f32 = 8.4 MB
    const size_t partBytes = (size_t)NJT * BSZ * 4 * sizeof(float);
    float* acc = (float*)(ws + anchorBytes + partBytes);                // 128 KB
    const size_t accBytes = (size_t)BSZ * 4 * sizeof(float);
    int* hist = (int*)(ws + anchorBytes + partBytes + accBytes);        // 4 KB

    zero_kernel<<<(NCLS + 255) / 256, 256, 0, stream>>>(hist);
    hist_kernel<<<BSZ / 256, 256, 0, stream>>>(labels, hist);
    norm_kernel<<<BSZ / 4, 256, 0, stream>>>(feat, anchor);
    dim3 grid(BSZ / BM, BSZ / BN);
    simloss_kernel<<<grid, 256, 0, stream>>>(anchor, labels, part);
    reduce_kernel<<<(BSZ * 4) / 256, 256, 0, stream>>>(part, acc);
    finalize_kernel<<<1, 256, 0, stream>>>(acc, labels, hist, out);
}

// Round 3
// 179.015 us; speedup vs baseline: 1.8978x; 1.0306x over previous
//
#include <hip/hip_runtime.h>

#define BSZ  8192
#define DDIM 256
#define NCLS 1024
#define BM 128
#define BN 128
#define BK 64
#define NT   64                 // tiles per dimension
#define NTRI (NT * (NT + 1) / 2) // 2080 upper-triangle tiles

typedef float f32x4 __attribute__((ext_vector_type(4)));
typedef short bf16x8 __attribute__((ext_vector_type(8)));

__device__ __forceinline__ unsigned short f32_to_bf16(float f) {
    unsigned int u = __float_as_uint(f);
    u += 0x7fffu + ((u >> 16) & 1u);   // RNE
    return (unsigned short)(u >> 16);
}
__device__ __forceinline__ float bf2f(unsigned short u) {
    return __uint_as_float(((unsigned int)u) << 16);
}

// ---------------- L2-normalize rows, emit bf16 ----------------
__global__ __launch_bounds__(256) void norm_kernel(const float* __restrict__ feat,
                                                   unsigned short* __restrict__ anchor) {
    const int wid  = threadIdx.x >> 6;
    const int lane = threadIdx.x & 63;
    const int row  = blockIdx.x * 4 + wid;
    const float4 v = ((const float4*)(feat + (size_t)row * DDIM))[lane];
    float ss = v.x * v.x + v.y * v.y + v.z * v.z + v.w * v.w;
    #pragma unroll
    for (int off = 32; off > 0; off >>= 1) ss += __shfl_xor(ss, off, 64);
    const float inv = rsqrtf(ss);
    ushort4 o;
    o.x = f32_to_bf16(v.x * inv);
    o.y = f32_to_bf16(v.y * inv);
    o.z = f32_to_bf16(v.z * inv);
    o.w = f32_to_bf16(v.w * inv);
    ((ushort4*)(anchor + (size_t)row * DDIM))[lane] = o;
}

// ---------------- async global -> LDS, 16B/lane ----------------
__device__ __forceinline__ void gload_lds16(const unsigned short* g, unsigned short* l) {
    __builtin_amdgcn_global_load_lds(
        (const __attribute__((address_space(1))) void*)g,
        (__attribute__((address_space(3))) void*)l, 16, 0, 0);
}

// epilogue constants
#define K_E1  20.60992915555662f    // (1/T)*log2(e)
#define K_E2 -20.60992915555662f
#define K_N1  1.4285714285714286f   // 1/(1-0.3)
#define K_N2  0.5714285714285714f   // 0.4/0.7

template <bool DIAG>
__device__ __forceinline__ void epilogue(
    const f32x4 (&c_acc)[4][4], int rg, int cl, int waveM, int waveN, bool dwave,
    float (*rowPart)[BM][2], float (*colPart)[BN][2])
{
    float cd[4] = {0.f, 0.f, 0.f, 0.f}, ct[4] = {0.f, 0.f, 0.f, 0.f};
    #pragma unroll
    for (int fr = 0; fr < 4; fr++) {
        float rd[4] = {0.f, 0.f, 0.f, 0.f}, rt[4] = {0.f, 0.f, 0.f, 0.f};
        #pragma unroll
        for (int fc = 0; fc < 4; fc++) {
            const f32x4 c = c_acc[fr][fc];
            #pragma unroll
            for (int r = 0; r < 4; r++) {
                const float s = c[r];
                float e = exp2f(fmaf(s, K_E1, K_E2));
                if (DIAG) {
                    if (fr == fc && dwave && (rg * 4 + r) == cl) e = 0.0f;
                }
                const float wn = fmaxf(fmaf(s, K_N1, K_N2), 1.0f);
                const float we = wn * e;
                rd[r] += e;  rt[r] += we;
                if (!DIAG) { cd[fc] += e; ct[fc] += we; }
            }
        }
        #pragma unroll
        for (int r = 0; r < 4; r++) {
            #pragma unroll
            for (int off = 1; off < 16; off <<= 1) {
                rd[r] += __shfl_xor(rd[r], off, 64);
                rt[r] += __shfl_xor(rt[r], off, 64);
            }
        }
        if (cl == 0) {
            const int wh = waveN >> 6;
            #pragma unroll
            for (int r = 0; r < 4; r++) {
                const int row = waveM + fr * 16 + rg * 4 + r;
                rowPart[wh][row][0] = rd[r];
                rowPart[wh][row][1] = rt[r];
            }
        }
    }
    if (!DIAG) {
        #pragma unroll
        for (int fc = 0; fc < 4; fc++) {
            #pragma unroll
            for (int off = 16; off < 64; off <<= 1) {
                cd[fc] += __shfl_xor(cd[fc], off, 64);
                ct[fc] += __shfl_xor(ct[fc], off, 64);
            }
        }
        if (rg == 0) {
            const int wmh = waveM >> 6;
            #pragma unroll
            for (int fc = 0; fc < 4; fc++) {
                const int col = waveN + fc * 16 + cl;
                colPart[wmh][col][0] = cd[fc];
                colPart[wmh][col][1] = ct[fc];
            }
        }
    }
}

// ---------------- fused sim-tile + loss partials (upper triangle) ----------------
// part[Jt][row][{0:dsum, 1:T2}]; every (slab,row) written exactly once.
__global__ __launch_bounds__(256) void simloss_kernel(
    const unsigned short* __restrict__ anchor,
    float* __restrict__ part)
{
    __shared__ __align__(16) unsigned short As[BM * BK];
    __shared__ __align__(16) unsigned short Bs[BN * BK];
    __shared__ float rowPart[2][BM][2];
    __shared__ float colPart[2][BN][2];

    // triangular decode: block t -> (It <= Jt)
    const int t = blockIdx.x;
    int It = (int)((129.0 - sqrt(16641.0 - 8.0 * (double)t)) * 0.5);
    if (It > 63) It = 63; if (It < 0) It = 0;
    #define CFUN(i) (64 * (i) - ((i) * ((i) - 1)) / 2)
    while (It < 63 && CFUN(It + 1) <= t) ++It;
    while (It > 0 && CFUN(It) > t) --It;
    const int Jt = It + (t - CFUN(It));
    const bool diag = (It == Jt);
    const int I0 = It * BM;
    const int J0 = Jt * BN;

    const int tid  = threadIdx.x;
    const int wid  = tid >> 6;
    const int lane = tid & 63;
    const int waveM = (wid >> 1) * 64;   // 2x2 wave grid over 128x128
    const int waveN = (wid & 1) * 64;
    const int cl = lane & 15;            // column within 16x16 frag
    const int rg = lane >> 4;            // row group (rows rg*4 + r)
    const bool dwave = diag && (waveM == waveN);

    f32x4 c_acc[4][4];
    #pragma unroll
    for (int a = 0; a < 4; a++)
        #pragma unroll
        for (int b = 0; b < 4; b++)
            c_acc[a][b] = (f32x4){0.f, 0.f, 0.f, 0.f};

    // staging: lane q loads global 16B chunk (q&7)^(row&7) of row q>>3 so that
    // LDS layout is XOR-swizzled (kills the 16-way ds_read_b128 bank conflict)
    const int ldrow = lane >> 3;                        // 0..7 within 8-row chunk
    const int ldcol = (((lane & 7) ^ ldrow) & 7) * 8;   // swizzled element offset

    for (int kc = 0; kc < DDIM; kc += BK) {
        #pragma unroll
        for (int q = 0; q < 4; q++) {
            const int ci = wid * 4 + q;            // chunk 0..15 -> rows ci*8..ci*8+7
            const int r  = ci * 8 + ldrow;
            gload_lds16(anchor + (size_t)(I0 + r) * DDIM + kc + ldcol, &As[ci * 512]);
            gload_lds16(anchor + (size_t)(J0 + r) * DDIM + kc + ldcol, &Bs[ci * 512]);
        }
        __syncthreads();
        #pragma unroll
        for (int ks = 0; ks < 2; ks++) {
            bf16x8 af[4], bfr[4];
            #pragma unroll
            for (int f = 0; f < 4; f++) {
                const int ra = waveM + f * 16 + cl;
                const int rb = waveN + f * 16 + cl;
                const int pa = ((ks * 4 + rg) ^ (ra & 7)) * 8;
                const int pb = ((ks * 4 + rg) ^ (rb & 7)) * 8;
                af[f]  = *(const bf16x8*)&As[ra * BK + pa];
                bfr[f] = *(const bf16x8*)&Bs[rb * BK + pb];
            }
            #pragma unroll
            for (int fr = 0; fr < 4; fr++)
                #pragma unroll
                for (int fc = 0; fc < 4; fc++)
                    c_acc[fr][fc] = __builtin_amdgcn_mfma_f32_16x16x32_bf16(
                        af[fr], bfr[fc], c_acc[fr][fc], 0, 0, 0);
        }
        __syncthreads();
    }

    if (diag) epilogue<true>(c_acc, rg, cl, waveM, waveN, dwave, rowPart, colPart);
    else      epilogue<false>(c_acc, rg, cl, waveM, waveN, dwave, rowPart, colPart);

    __syncthreads();
    if (tid < BM) {
        float2 v;
        v.x = rowPart[0][tid][0] + rowPart[1][tid][0];
        v.y = rowPart[0][tid][1] + rowPart[1][tid][1];
        ((float2*)part)[(size_t)Jt * BSZ + I0 + tid] = v;
    } else if (!diag) {
        const int c = tid - BM;
        float2 v;
        v.x = colPart[0][c][0] + colPart[1][c][0];
        v.y = colPart[0][c][1] + colPart[1][c][1];
        ((float2*)part)[(size_t)It * BSZ + J0 + c] = v;
    }
}

// ---------------- per-class positive terms (no atomics: one class owns each row) ----------------
// posout[row] = {s1, w1, pcorr, h}
__global__ __launch_bounds__(256) void posfix_kernel(
    const unsigned short* __restrict__ anchor,
    const int* __restrict__ labels,
    float* __restrict__ posout)
{
    __shared__ int rows[BSZ];
    __shared__ int cnt;
    const int c = blockIdx.x;
    const int tid = threadIdx.x;
    if (tid == 0) cnt = 0;
    __syncthreads();
    for (int i = tid; i < BSZ; i += 256)
        if (labels[i] == c) { int p = atomicAdd(&cnt, 1); rows[p] = i; }
    __syncthreads();
    const int h = cnt;
    if (h == 0) return;
    const int wid = tid >> 6, lane = tid & 63;
    for (int a = wid; a < h; a += 4) {
        const int ra = rows[a];
        const ushort4 va = ((const ushort4*)(anchor + (size_t)ra * DDIM))[lane];
        const float a0 = bf2f(va.x), a1 = bf2f(va.y), a2 = bf2f(va.z), a3 = bf2f(va.w);
        float s1 = 0.f, w1 = 0.f, pcorr = 0.f;
        for (int b = 0; b < h; b++) {
            if (b == a) continue;
            const int rb = rows[b];
            const ushort4 vb = ((const ushort4*)(anchor + (size_t)rb * DDIM))[lane];
            float d = a0 * bf2f(vb.x) + a1 * bf2f(vb.y) + a2 * bf2f(vb.z) + a3 * bf2f(vb.w);
            #pragma unroll
            for (int o = 32; o > 0; o >>= 1) d += __shfl_xor(d, o, 64);
            const float s  = d;
            const float e  = exp2f(fmaf(s, K_E1, K_E2));
            const float lp = (s - 1.0f) * 14.285714285714286f;
            const float wp = fmaxf(1.5f - s, 1.0f);
            const float wn = fmaxf(fmaf(s, K_N1, K_N2), 1.0f);
            s1 = fmaf(wp, lp, s1);
            w1 += wp;
            pcorr = fmaf(wn, e, pcorr);
        }
        if (lane == 0) {
            float4 o; o.x = s1; o.y = w1; o.z = pcorr; o.w = (float)h;
            ((float4*)posout)[ra] = o;
        }
    }
}

// ---------------- per-row combine + block partial sums ----------------
__global__ __launch_bounds__(256) void reduce_kernel(
    const float* __restrict__ part, const float* __restrict__ posout,
    double* __restrict__ partial)
{
    const int i = blockIdx.x * 256 + threadIdx.x;
    float dsum = 0.f, T2 = 0.f;
    const float2* p2 = (const float2*)part;
    #pragma unroll 8
    for (int j = 0; j < NT; j++) {
        const float2 v = p2[(size_t)j * BSZ + i];
        dsum += v.x; T2 += v.y;
    }
    const float4 po = ((const float4*)posout)[i];
    const float s1 = po.x, w1 = po.y, pcorr = po.z;
    const int h = (int)po.w;
    const float pc = fmaxf((float)(h - 1), 1.0f);
    const float nc = fmaxf((float)(BSZ - h), 1.0f);
    const float ld = logf(dsum);
    const double pos_i = (double)((s1 - ld * w1) / pc);
    const double neg_i = (double)(((T2 - pcorr) / dsum) / nc);

    __shared__ double sp[256], sn[256];
    sp[threadIdx.x] = pos_i; sn[threadIdx.x] = neg_i;
    __syncthreads();
    for (int s = 128; s > 0; s >>= 1) {
        if (threadIdx.x < s) {
            sp[threadIdx.x] += sp[threadIdx.x + s];
            sn[threadIdx.x] += sn[threadIdx.x + s];
        }
        __syncthreads();
    }
    if (threadIdx.x == 0) {
        partial[blockIdx.x * 2 + 0] = sp[0];
        partial[blockIdx.x * 2 + 1] = sn[0];
    }
}

// ---------------- final scalar ----------------
__global__ __launch_bounds__(64) void final_kernel(const double* __restrict__ partial,
                                                   float* __restrict__ out) {
    const int lane = threadIdx.x;
    double p = 0.0, n = 0.0;
    if (lane < 32) { p = partial[lane * 2 + 0]; n = partial[lane * 2 + 1]; }
    #pragma unroll
    for (int o = 32; o > 0; o >>= 1) { p += __shfl_xor(p, o, 64); n += __shfl_xor(n, o, 64); }
    if (lane == 0) out[0] = (float)(-p / (double)BSZ + 0.3 * (n / (double)BSZ));
}

extern "C" void kernel_launch(void* const* d_in, const int* in_sizes, int n_in,
                              void* d_out, int out_size, void* d_ws, size_t ws_size,
                              hipStream_t stream) {
    const float* feat = (const float*)d_in[0];
    const int* labels = (const int*)d_in[1];
    float* out = (float*)d_out;

    char* ws = (char*)d_ws;
    unsigned short* anchor = (unsigned short*)ws;                        // 4 MB bf16
    const size_t anchorBytes = (size_t)BSZ * DDIM * sizeof(unsigned short);
    float* part = (float*)(ws + anchorBytes);                            // 64*8192*2 f32 = 4 MB
    const size_t partBytes = (size_t)NT * BSZ * 2 * sizeof(float);
    float* posout = (float*)(ws + anchorBytes + partBytes);              // 128 KB
    const size_t posBytes = (size_t)BSZ * 4 * sizeof(float);
    double* partial = (double*)(ws + anchorBytes + partBytes + posBytes); // 512 B

    norm_kernel<<<BSZ / 4, 256, 0, stream>>>(feat, anchor);
    simloss_kernel<<<NTRI, 256, 0, stream>>>(anchor, part);
    posfix_kernel<<<NCLS, 256, 0, stream>>>(anchor, labels, posout);
    reduce_kernel<<<BSZ / 256, 256, 0, stream>>>(part, posout, partial);
    final_kernel<<<1, 64, 0, stream>>>(partial, out);
}